// Round 1
// baseline (124.706 us; speedup 1.0000x reference)
//
#include <hip/hip_runtime.h>
#include <hip/hip_bf16.h>
#include <math.h>

// Problem constants (fixed by setup_inputs in the reference)
#define BB 4
#define SS 1024
#define LL 128

// Kernel 1: per-row logsumexp over pred (B*S rows of length L=128).
// One wave (64 lanes) per row; each lane holds 2 consecutive elements (float2).
// Produces:
//   ws_emit[b]  += sum_t (pred[b,t,gt[b,t]] - lse[b,t])   (atomic, pre-zeroed)
//   ws_logp0[b*L + l] = pred[b,0,l] - lse[b,0]
__global__ __launch_bounds__(256) void crf_rows_kernel(
    const float* __restrict__ pred,
    const int* __restrict__ gt,
    float* __restrict__ ws_emit,
    float* __restrict__ ws_logp0)
{
    const int wave = threadIdx.x >> 6;   // 0..3
    const int lane = threadIdx.x & 63;
    const int row0 = blockIdx.x * 16;    // 16 rows per block, 4 per wave
    const int b = row0 / SS;             // 16 divides 1024 -> single b per block

    float local_emit = 0.0f;
    for (int it = 0; it < 4; ++it) {
        const int r = row0 + it * 4 + wave;
        const float2* rowp = (const float2*)(pred + (size_t)r * LL);
        float2 v = rowp[lane];           // elements 2*lane, 2*lane+1

        float m = fmaxf(v.x, v.y);
        #pragma unroll
        for (int off = 32; off > 0; off >>= 1) m = fmaxf(m, __shfl_xor(m, off));
        float s = __expf(v.x - m) + __expf(v.y - m);
        #pragma unroll
        for (int off = 32; off > 0; off >>= 1) s += __shfl_xor(s, off);
        const float lse = m + __logf(s);

        if (lane == 0) {
            const int g = gt[r];
            local_emit += pred[(size_t)r * LL + g] - lse;
        }
        if ((r & (SS - 1)) == 0) {       // t == 0 row: stash logp0
            const int bb = r / SS;
            ws_logp0[bb * LL + 2 * lane]     = v.x - lse;
            ws_logp0[bb * LL + 2 * lane + 1] = v.y - lse;
        }
    }

    __shared__ float red[4];
    if (lane == 0) red[wave] = local_emit;
    __syncthreads();
    if (threadIdx.x == 0) {
        atomicAdd(&ws_emit[b], red[0] + red[1] + red[2] + red[3]);
    }
}

// Kernel 2: everything L x L, single block of 128 threads.
__global__ __launch_bounds__(128) void crf_finish_kernel(
    const float* __restrict__ transition,
    const int* __restrict__ gt,
    const float* __restrict__ ws_emit,
    const float* __restrict__ ws_logp0,
    float* __restrict__ out)
{
    __shared__ float tr_s[LL][LL + 1];   // +1 pad: conflict-free column reads
    __shared__ float logp0_s[BB][LL];
    __shared__ float c_s[LL];
    __shared__ float red[LL];

    const int tid = threadIdx.x;         // 0..127

    // cooperative coalesced load of transition into LDS
    for (int i = 0; i < LL; ++i) tr_s[i][tid] = transition[i * LL + tid];
    for (int b = 0; b < BB; ++b) logp0_s[b][tid] = ws_logp0[b * LL + tid];
    __syncthreads();

    // row log-softmax: thread tid owns row tid
    {
        float m = -INFINITY;
        for (int j = 0; j < LL; ++j) m = fmaxf(m, tr_s[tid][j]);
        float s = 0.0f;
        for (int j = 0; j < LL; ++j) s += __expf(tr_s[tid][j] - m);
        const float lse = m + __logf(s);
        for (int j = 0; j < LL; ++j) tr_s[tid][j] -= lse;
    }
    __syncthreads();

    // c[j] = lse_i trans[i][j]: thread tid owns column tid
    {
        float m = -INFINITY;
        for (int i = 0; i < LL; ++i) m = fmaxf(m, tr_s[i][tid]);
        float s = 0.0f;
        for (int i = 0; i < LL; ++i) s += __expf(tr_s[i][tid] - m);
        c_s[tid] = m + __logf(s);
    }
    // (thread reads only its own c_s[tid] later; tr_s stable from here on)

    float total = 0.0f;                  // thread 0: sum_b (gold_b - forward_b)
    for (int b = 0; b < BB; ++b) {
        // gold transition-path sum
        float loc = 0.0f;
        for (int t = tid; t < SS - 1; t += LL) {
            loc += tr_s[gt[b * SS + t]][gt[b * SS + t + 1]];
        }
        red[tid] = loc;
        __syncthreads();
        #pragma unroll
        for (int off = 64; off > 0; off >>= 1) {
            if (tid < off) red[tid] += red[tid + off];
            __syncthreads();
        }
        const float trb = red[0];
        __syncthreads();

        // alpha[j] for j = tid
        float am = -INFINITY;
        for (int i = 0; i < LL; ++i) am = fmaxf(am, tr_s[i][tid] + logp0_s[b][i]);
        float as = 0.0f;
        for (int i = 0; i < LL; ++i) as += __expf(tr_s[i][tid] + logp0_s[b][i] - am);
        const float alpha = am + __logf(as) + (float)(SS - 2) * c_s[tid];

        // forward_b = lse_j alpha[j]
        red[tid] = alpha;
        __syncthreads();
        #pragma unroll
        for (int off = 64; off > 0; off >>= 1) {
            if (tid < off) red[tid] = fmaxf(red[tid], red[tid + off]);
            __syncthreads();
        }
        const float amax = red[0];
        __syncthreads();
        red[tid] = __expf(alpha - amax);
        __syncthreads();
        #pragma unroll
        for (int off = 64; off > 0; off >>= 1) {
            if (tid < off) red[tid] += red[tid + off];
            __syncthreads();
        }
        const float fwd = amax + __logf(red[0]);
        __syncthreads();

        if (tid == 0) total += ws_emit[b] + trb - fwd;
    }

    if (tid == 0) out[0] = -total * (1.0f / BB);
}

extern "C" void kernel_launch(void* const* d_in, const int* in_sizes, int n_in,
                              void* d_out, int out_size, void* d_ws, size_t ws_size,
                              hipStream_t stream) {
    const float* pred       = (const float*)d_in[0];
    const int*   gt         = (const int*)d_in[1];
    const float* transition = (const float*)d_in[2];
    float* out = (float*)d_out;

    float* ws_emit  = (float*)d_ws;        // BB floats (zeroed below)
    float* ws_logp0 = ws_emit + BB;        // BB*LL floats (fully overwritten)

    hipMemsetAsync(ws_emit, 0, BB * sizeof(float), stream);
    crf_rows_kernel<<<(BB * SS) / 16, 256, 0, stream>>>(pred, gt, ws_emit, ws_logp0);
    crf_finish_kernel<<<1, LL, 0, stream>>>(transition, gt, ws_emit, ws_logp0, out);
}

// Round 2
// 70.733 us; speedup vs baseline: 1.7631x; 1.7631x over previous
//
#include <hip/hip_runtime.h>
#include <hip/hip_bf16.h>
#include <math.h>

#define BB 4
#define SS 1024
#define LL 128

// Kernel 1: per-row logsumexp over pred (B*S rows of length L=128).
// One wave per row-slot; 16 rows per block (4 per wave, sequential).
// Writes ws_part[block] = sum_t(pred[t,gt[t]] - lse[t]) over the block's rows
// (no atomics, no pre-zeroing needed), and ws_logp0[b,:] for the t==0 rows.
__global__ __launch_bounds__(256) void crf_rows_kernel(
    const float* __restrict__ pred,
    const int* __restrict__ gt,
    float* __restrict__ ws_part,
    float* __restrict__ ws_logp0)
{
    const int wave = threadIdx.x >> 6;
    const int lane = threadIdx.x & 63;
    const int row0 = blockIdx.x * 16;

    // issue all global loads up front so latencies overlap
    float2 v[4];
    #pragma unroll
    for (int it = 0; it < 4; ++it) {
        const int r = row0 + it * 4 + wave;
        v[it] = ((const float2*)(pred + (size_t)r * LL))[lane];
    }
    float gval[4] = {0.f, 0.f, 0.f, 0.f};
    if (lane == 0) {
        int gi[4];
        #pragma unroll
        for (int it = 0; it < 4; ++it) gi[it] = gt[row0 + it * 4 + wave];
        #pragma unroll
        for (int it = 0; it < 4; ++it)
            gval[it] = pred[(size_t)(row0 + it * 4 + wave) * LL + gi[it]];
    }

    float local = 0.f;
    #pragma unroll
    for (int it = 0; it < 4; ++it) {
        float m = fmaxf(v[it].x, v[it].y);
        #pragma unroll
        for (int off = 32; off > 0; off >>= 1) m = fmaxf(m, __shfl_xor(m, off));
        float s = __expf(v[it].x - m) + __expf(v[it].y - m);
        #pragma unroll
        for (int off = 32; off > 0; off >>= 1) s += __shfl_xor(s, off);
        const float lse = m + __logf(s);

        if (lane == 0) local += gval[it] - lse;

        // t == 0 rows: r in {0,1024,2048,3072}
        if (it == 0 && wave == 0 && (blockIdx.x & 63) == 0) {
            const int b = blockIdx.x >> 6;
            ws_logp0[b * LL + 2 * lane]     = v[0].x - lse;
            ws_logp0[b * LL + 2 * lane + 1] = v[0].y - lse;
        }
    }

    __shared__ float red[4];
    if (lane == 0) red[wave] = local;
    __syncthreads();
    if (threadIdx.x == 0)
        ws_part[blockIdx.x] = red[0] + red[1] + red[2] + red[3];
}

// Kernel 2: all L x L work, 1 block x 512 threads (8 waves).
__global__ __launch_bounds__(512) void crf_finish_kernel(
    const float* __restrict__ transition,
    const int* __restrict__ gt,
    const float* __restrict__ ws_part,
    const float* __restrict__ ws_logp0,
    float* __restrict__ out)
{
    __shared__ float tr_s[LL][LL + 1];     // pad +1: 2-way max aliasing (free)
    __shared__ float logp0_s[BB][LL];
    __shared__ float redm[4][LL];
    __shared__ float reds[4][LL];
    __shared__ float lse_s[LL];
    __shared__ float c_s[LL];
    __shared__ float emit_s[BB];
    __shared__ float gold_s[BB];
    __shared__ float wred[16];

    const int tid  = threadIdx.x;
    const int lane = tid & 63;
    const int wave = tid >> 6;

    // ---- loads ----
    for (int idx = tid; idx < LL * LL; idx += 512)
        tr_s[idx >> 7][idx & (LL - 1)] = transition[idx];
    if (tid < BB * LL)
        logp0_s[tid >> 7][tid & (LL - 1)] = ws_logp0[tid];
    if (wave < BB) {  // wave w reduces the 64 block-partials of batch w
        float p = ws_part[wave * 64 + lane];
        #pragma unroll
        for (int off = 32; off > 0; off >>= 1) p += __shfl_xor(p, off);
        if (lane == 0) emit_s[wave] = p;
    }
    __syncthreads();                                        // (A)

    // ---- row log-softmax of transition: sub=tid>>7 owns 32 cols of row ----
    const int sub = tid >> 7;          // 0..3
    const int rc  = tid & 127;         // row (here) / col (later)
    {
        const float* rp = &tr_s[rc][sub * 32];
        float m = -INFINITY;
        #pragma unroll
        for (int k = 0; k < 32; ++k) m = fmaxf(m, rp[k]);
        float s = 0.f;
        #pragma unroll
        for (int k = 0; k < 32; ++k) s += __expf(rp[k] - m);
        redm[sub][rc] = m;
        reds[sub][rc] = s;
    }
    __syncthreads();                                        // (B)
    if (tid < LL) {
        float m0 = redm[0][tid], m1 = redm[1][tid], m2 = redm[2][tid], m3 = redm[3][tid];
        float mm = fmaxf(fmaxf(m0, m1), fmaxf(m2, m3));
        float ss = reds[0][tid] * __expf(m0 - mm) + reds[1][tid] * __expf(m1 - mm)
                 + reds[2][tid] * __expf(m2 - mm) + reds[3][tid] * __expf(m3 - mm);
        lse_s[tid] = mm + __logf(ss);
    }
    __syncthreads();                                        // (C)
    {
        const float l = lse_s[rc];
        float* wp = &tr_s[rc][sub * 32];
        #pragma unroll
        for (int k = 0; k < 32; ++k) wp[k] -= l;
    }
    __syncthreads();                                        // (D)

    // ---- column LSE partials (for c[j]) + gold path sum (both read-only) ----
    {
        float m = -INFINITY;
        #pragma unroll
        for (int k = 0; k < 32; ++k) m = fmaxf(m, tr_s[sub * 32 + k][rc]);
        float s = 0.f;
        #pragma unroll
        for (int k = 0; k < 32; ++k) s += __expf(tr_s[sub * 32 + k][rc] - m);
        redm[sub][rc] = m;
        reds[sub][rc] = s;
    }
    {
        const int b  = tid >> 7;       // 0..3
        const int t0 = tid & 127;
        const int* gtb = gt + b * SS;
        float g = 0.f;
        for (int t = t0; t < SS - 1; t += 128)
            g += tr_s[gtb[t]][gtb[t + 1]];
        #pragma unroll
        for (int off = 32; off > 0; off >>= 1) g += __shfl_xor(g, off);
        if (lane == 0) wred[wave] = g;
    }
    __syncthreads();                                        // (E)
    if (tid < LL) {
        float m0 = redm[0][tid], m1 = redm[1][tid], m2 = redm[2][tid], m3 = redm[3][tid];
        float mm = fmaxf(fmaxf(m0, m1), fmaxf(m2, m3));
        float ss = reds[0][tid] * __expf(m0 - mm) + reds[1][tid] * __expf(m1 - mm)
                 + reds[2][tid] * __expf(m2 - mm) + reds[3][tid] * __expf(m3 - mm);
        c_s[tid] = mm + __logf(ss);
    }
    if (tid < BB)
        gold_s[tid] = wred[2 * tid] + wred[2 * tid + 1];
    __syncthreads();                                        // (F)

    // ---- alpha[b,j] via online LSE over i; thread = (b,j) ----
    const int b = tid >> 7;
    const int j = tid & 127;
    float am = -INFINITY, as = 0.f;
    const float* lp = logp0_s[b];
    for (int i = 0; i < LL; ++i) {
        const float v  = tr_s[i][j] + lp[i];
        const float mn = fmaxf(am, v);
        as = as * __expf(am - mn) + __expf(v - mn);
        am = mn;
    }
    const float alpha = am + __logf(as) + (float)(SS - 2) * c_s[j];

    // ---- forward[b] = lse_j alpha; 2 waves per b ----
    float wm = alpha;
    #pragma unroll
    for (int off = 32; off > 0; off >>= 1) wm = fmaxf(wm, __shfl_xor(wm, off));
    float wsum = __expf(alpha - wm);
    #pragma unroll
    for (int off = 32; off > 0; off >>= 1) wsum += __shfl_xor(wsum, off);
    if (lane == 0) { redm[0][wave] = wm; reds[0][wave] = wsum; }
    __syncthreads();                                        // (G)
    if (tid < BB) {
        const float m0 = redm[0][2 * tid], m1 = redm[0][2 * tid + 1];
        const float mm = fmaxf(m0, m1);
        const float ss = reds[0][2 * tid] * __expf(m0 - mm)
                       + reds[0][2 * tid + 1] * __expf(m1 - mm);
        const float fwd = mm + __logf(ss);
        wred[tid] = emit_s[tid] + gold_s[tid] - fwd;
    }
    __syncthreads();                                        // (H)
    if (tid == 0)
        out[0] = -(wred[0] + wred[1] + wred[2] + wred[3]) * (1.0f / BB);
}

extern "C" void kernel_launch(void* const* d_in, const int* in_sizes, int n_in,
                              void* d_out, int out_size, void* d_ws, size_t ws_size,
                              hipStream_t stream) {
    const float* pred       = (const float*)d_in[0];
    const int*   gt         = (const int*)d_in[1];
    const float* transition = (const float*)d_in[2];
    float* out = (float*)d_out;

    float* ws_part  = (float*)d_ws;        // 256 floats, fully written by rows
    float* ws_logp0 = ws_part + 256;       // BB*LL floats, fully written

    crf_rows_kernel<<<(BB * SS) / 16, 256, 0, stream>>>(pred, gt, ws_part, ws_logp0);
    crf_finish_kernel<<<1, 512, 0, stream>>>(transition, gt, ws_part, ws_logp0, out);
}

// Round 3
// 64.495 us; speedup vs baseline: 1.9336x; 1.0967x over previous
//
#include <hip/hip_runtime.h>
#include <hip/hip_bf16.h>
#include <math.h>

#define BB 4
#define SS 1024
#define LL 128

// ws layout (floats): [0..255] ws_part, [256..767] ws_elp (4 x 128, exp(logp0)),
// [768..768+16383] ws_trans (row-log-softmaxed transition). 768*4 B = 16B-aligned.

// Kernel 1: 256 blocks x 256 threads.
//  - every block: 16 pred rows -> row-LSE -> emit partial ws_part[block]
//  - blocks b*64 (b<4): wave 0 also writes ws_elp[b][:] = exp(pred[b,0,:]-lse)
//  - blocks r<128: wave 0 also row-log-softmaxes transition row r -> ws_trans
__global__ __launch_bounds__(256) void crf_rows_kernel(
    const float* __restrict__ pred,
    const int* __restrict__ gt,
    const float* __restrict__ transition,
    float* __restrict__ ws_part,
    float* __restrict__ ws_elp,
    float* __restrict__ ws_trans)
{
    const int wave = threadIdx.x >> 6;
    const int lane = threadIdx.x & 63;
    const int row0 = blockIdx.x * 16;

    // issue all global loads up front so latencies overlap
    float2 v[4];
    #pragma unroll
    for (int it = 0; it < 4; ++it) {
        const int r = row0 + it * 4 + wave;
        v[it] = ((const float2*)(pred + (size_t)r * LL))[lane];
    }
    float gval[4] = {0.f, 0.f, 0.f, 0.f};
    if (lane == 0) {
        int gi[4];
        #pragma unroll
        for (int it = 0; it < 4; ++it) gi[it] = gt[row0 + it * 4 + wave];
        #pragma unroll
        for (int it = 0; it < 4; ++it)
            gval[it] = pred[(size_t)(row0 + it * 4 + wave) * LL + gi[it]];
    }

    float local = 0.f;
    #pragma unroll
    for (int it = 0; it < 4; ++it) {
        float m = fmaxf(v[it].x, v[it].y);
        #pragma unroll
        for (int off = 32; off > 0; off >>= 1) m = fmaxf(m, __shfl_xor(m, off));
        float s = __expf(v[it].x - m) + __expf(v[it].y - m);
        #pragma unroll
        for (int off = 32; off > 0; off >>= 1) s += __shfl_xor(s, off);
        const float lse = m + __logf(s);

        if (lane == 0) local += gval[it] - lse;

        // t == 0 rows live in blocks {0,64,128,192}: stash exp(logp0)
        if (it == 0 && wave == 0 && (blockIdx.x & 63) == 0) {
            const int b = blockIdx.x >> 6;
            ws_elp[b * LL + 2 * lane]     = __expf(v[0].x - lse);
            ws_elp[b * LL + 2 * lane + 1] = __expf(v[0].y - lse);
        }
    }

    // transition row-log-softmax: block r (<128), wave 0
    if (blockIdx.x < LL && wave == 0) {
        const float2 tv = ((const float2*)(transition + blockIdx.x * LL))[lane];
        float m = fmaxf(tv.x, tv.y);
        #pragma unroll
        for (int off = 32; off > 0; off >>= 1) m = fmaxf(m, __shfl_xor(m, off));
        float s = __expf(tv.x - m) + __expf(tv.y - m);
        #pragma unroll
        for (int off = 32; off > 0; off >>= 1) s += __shfl_xor(s, off);
        const float lse = m + __logf(s);
        float2 o; o.x = tv.x - lse; o.y = tv.y - lse;
        ((float2*)(ws_trans + blockIdx.x * LL))[lane] = o;
    }

    __shared__ float red[4];
    if (lane == 0) red[wave] = local;
    __syncthreads();
    if (threadIdx.x == 0)
        ws_part[blockIdx.x] = red[0] + red[1] + red[2] + red[3];
}

// Kernel 2: 1 block x 512 threads. Inputs are pre-softmaxed; only column
// exp-sums (no max shift needed: tr_ls <= 0, elp <= 1), gold gathers, and
// two short LSE reductions remain.
#define PADL (LL + 4)   // stride 132 floats = 528 B: 16B-aligned rows, (4i+j)%32 banks
__global__ __launch_bounds__(512) void crf_finish_kernel(
    const int* __restrict__ gt,
    const float* __restrict__ ws_part,
    const float* __restrict__ ws_elp,
    const float* __restrict__ ws_trans,
    float* __restrict__ out)
{
    __shared__ float tr_s[LL][PADL];
    __shared__ float elp_s[BB][LL];
    __shared__ float pc[4][LL];        // column exp-sum partials (c)
    __shared__ float pa[4][BB][LL];    // column exp-sum partials (alpha)
    __shared__ float emit_s[BB];
    __shared__ float wred[8];          // gold per-wave partials
    __shared__ float fm[8], fs[8];     // forward LSE per-wave partials

    const int tid  = threadIdx.x;
    const int lane = tid & 63;
    const int wave = tid >> 6;

    // ---- loads ----
    #pragma unroll
    for (int k = 0; k < 8; ++k) {               // 4096 float4s, 8 per thread
        const int e = (tid + k * 512) * 4;      // element index
        const int i = e >> 7, j = e & (LL - 1);
        *(float4*)&tr_s[i][j] = ((const float4*)ws_trans)[e >> 2];
    }
    elp_s[tid >> 7][tid & (LL - 1)] = ws_elp[tid];
    if (wave < BB) {                            // emit: wave w reduces batch w
        float p = ws_part[wave * 64 + lane];
        #pragma unroll
        for (int off = 32; off > 0; off >>= 1) p += __shfl_xor(p, off);
        if (lane == 0) emit_s[wave] = p;
    }
    __syncthreads();                                        // (A)

    // ---- column partials: thread (sub,j), sub owns 32 rows ----
    {
        const int sub = tid >> 7;
        const int j   = tid & (LL - 1);
        float sc = 0.f, s0 = 0.f, s1 = 0.f, s2 = 0.f, s3 = 0.f;
        #pragma unroll
        for (int k = 0; k < 32; ++k) {
            const int i = sub * 32 + k;
            const float e = __expf(tr_s[i][j]);
            sc += e;
            s0 += e * elp_s[0][i];
            s1 += e * elp_s[1][i];
            s2 += e * elp_s[2][i];
            s3 += e * elp_s[3][i];
        }
        pc[sub][j] = sc;
        pa[sub][0][j] = s0; pa[sub][1][j] = s1;
        pa[sub][2][j] = s2; pa[sub][3][j] = s3;
    }
    // ---- gold path partials (tr_s read-only here) ----
    {
        const int b  = tid >> 7;
        const int t0 = tid & (LL - 1);
        const int* gtb = gt + b * SS;
        float g = 0.f;
        for (int t = t0; t < SS - 1; t += LL)
            g += tr_s[gtb[t]][gtb[t + 1]];
        #pragma unroll
        for (int off = 32; off > 0; off >>= 1) g += __shfl_xor(g, off);
        if (lane == 0) wred[wave] = g;
    }
    __syncthreads();                                        // (B)

    // ---- alpha[b,j] + per-wave forward LSE partials ----
    {
        const int b = tid >> 7;
        const int j = tid & (LL - 1);
        const float csum = pc[0][j] + pc[1][j] + pc[2][j] + pc[3][j];
        const float asum = pa[0][b][j] + pa[1][b][j] + pa[2][b][j] + pa[3][b][j];
        const float alpha = __logf(asum) + (float)(SS - 2) * __logf(csum);

        float wm = alpha;
        #pragma unroll
        for (int off = 32; off > 0; off >>= 1) wm = fmaxf(wm, __shfl_xor(wm, off));
        float wsum = __expf(alpha - wm);
        #pragma unroll
        for (int off = 32; off > 0; off >>= 1) wsum += __shfl_xor(wsum, off);
        if (lane == 0) { fm[wave] = wm; fs[wave] = wsum; }
    }
    __syncthreads();                                        // (C)

    if (tid < BB) {
        const float m0 = fm[2 * tid], m1 = fm[2 * tid + 1];
        const float mm = fmaxf(m0, m1);
        const float fwd = mm + __logf(fs[2 * tid] * __expf(m0 - mm)
                                    + fs[2 * tid + 1] * __expf(m1 - mm));
        const float gold = wred[2 * tid] + wred[2 * tid + 1];
        fm[tid] = emit_s[tid] + gold - fwd;   // reuse fm as loss scratch
    }
    __syncthreads();                                        // (D)
    if (tid == 0)
        out[0] = -(fm[0] + fm[1] + fm[2] + fm[3]) * (1.0f / BB);
}

extern "C" void kernel_launch(void* const* d_in, const int* in_sizes, int n_in,
                              void* d_out, int out_size, void* d_ws, size_t ws_size,
                              hipStream_t stream) {
    const float* pred       = (const float*)d_in[0];
    const int*   gt         = (const int*)d_in[1];
    const float* transition = (const float*)d_in[2];
    float* out = (float*)d_out;

    float* ws_part  = (float*)d_ws;        // 256 floats
    float* ws_elp   = ws_part + 256;       // 512 floats
    float* ws_trans = ws_part + 768;       // 16384 floats, 16B-aligned offset

    crf_rows_kernel<<<(BB * SS) / 16, 256, 0, stream>>>(
        pred, gt, transition, ws_part, ws_elp, ws_trans);
    crf_finish_kernel<<<1, 512, 0, stream>>>(gt, ws_part, ws_elp, ws_trans, out);
}